// Round 15
// baseline (104.076 us; speedup 1.0000x reference)
//
#include <hip/hip_runtime.h>

#define HW_    56
#define C_     128
#define SHIFT_ 3
#define NH_    4
#define NT_    49

typedef __attribute__((ext_vector_type(8))) __bf16 bf16x8;
typedef __attribute__((ext_vector_type(4))) float  f32x4;
typedef __attribute__((ext_vector_type(4))) short  s16x4;

// d_ws layout:
//   shorts [0, 65536)       : wt2 (24 qkv oc-tiles) then wp2 (8 proj oc-tiles),
//                             FRAGMENT-CONTIGUOUS (R12): block (tile,ks)=512 bf16,
//                             lane L holds (oc=tile*16+(L&15), ic=ks*32+(L>>4)*8+e).
//   bytes [131072, +200704) : f32 cb[cls=4][h=4][q=49][k=64] — bias+mask
//                             (post-softmax). Mask depends ONLY on (wi==7,wj==7).
#define WS_CB_BYTE  131072
#define CB_ELEMS    (4 * 4 * 49 * 64)

// LDS 29440 B. R15: __launch_bounds__(256,5) — LDS permits 5 blocks/CU
// (147.2/160 KB); peak live-set audit (~90-95 regs) fits the 102-reg budget
// (unlike R9/R10 designs which peaked >=130 and spilled). Spill diagnosis:
// WRITE_SIZE > 100352 KB.
// [0,12800) X / X2 overlay; [12800,29184) V per head (keys>=49 ZERO —
// PV reduction axis, NaN*0=NaN); [29184,29380) toff. Q,K,S,P reg-resident.
// Softmax without max-subtraction (R14): S=QK^T pre-bias, |S|<~0.5 here;
// exp overflow needs |S|>80; softmax shift-invariant.
#define XB    0
#define VB    12800
#define TOFFB 29184
#define SMEMB 29440

__device__ __forceinline__ int q4(int g, int tok) { return g * 784 + (tok << 4); }
__device__ __forceinline__ int swzv(int g, int row) {
    return (((g << 9) + (row << 4)) ^ ((g & 7) << 4));
}
__device__ __forceinline__ unsigned short bfbits(float f) {
    __bf16 h = (__bf16)f;
    union { __bf16 b; unsigned short u; } c; c.b = h; return c.u;
}

// ---- fused prep: weights (frag-contiguous bf16) + cb class table ----
__global__ void prep(const float* __restrict__ wq, const float* __restrict__ wp,
                     const float* __restrict__ rel, unsigned short* __restrict__ ws,
                     float* __restrict__ cb) {
    int i = blockIdx.x * 256 + threadIdx.x;
    if (i < 49152) {
        const int mt   = i >> 11;
        const int ks   = (i >> 9) & 3;
        const int lane = (i >> 3) & 63;
        const int e    = i & 7;
        const int oc   = mt * 16 + (lane & 15);
        const int ic   = ks * 32 + (lane >> 4) * 8 + e;
        ws[i] = bfbits(wq[ic * 384 + oc]);
    } else if (i < 65536) {
        const int j    = i - 49152;
        const int t    = j >> 11;
        const int ks   = (j >> 9) & 3;
        const int lane = (j >> 3) & 63;
        const int e    = j & 7;
        const int oc   = t * 16 + (lane & 15);
        const int ic   = ks * 32 + (lane >> 4) * 8 + e;
        ws[i] = bfbits(wp[ic * 128 + oc]);
    } else {
        const int j = i - 65536;
        if (j < CB_ELEMS) {
            const int k = j & 63;
            const int t = j >> 6;          // (cls*4 + h)*49 + q
            const int q = t % 49;
            const int u = t / 49;
            const int h = u & 3;
            const int cls = u >> 2;        // 2*(wi==7) + (wj==7)
            float v = 0.f;
            if (k < 49) {
                const int iq = q / 7, jq = q - 7 * iq;
                const int ik = k / 7, jk = k - 7 * ik;
                v = rel[((iq - ik + 6) * 13 + (jq - jk + 6)) * NH_ + h];
                const int rq = ((cls >> 1) ? (iq < 4 ? 1 : 2) : 0) * 3
                             + ((cls & 1) ? (jq < 4 ? 1 : 2) : 0);
                const int rk = ((cls >> 1) ? (ik < 4 ? 1 : 2) : 0) * 3
                             + ((cls & 1) ? (jk < 4 ? 1 : 2) : 0);
                if (rq != rk) v -= 100.0f;
            }
            cb[j] = v;
        }
    }
}

__global__ __launch_bounds__(256, 5)
void swin_fused(const float* __restrict__ x,
                const float* __restrict__ b_qkv,
                const float* __restrict__ b_proj,
                const unsigned short* __restrict__ wsb,
                const float* __restrict__ cb,
                float* __restrict__ out)
{
    extern __shared__ char smc[];
    const __bf16* wt2 = (const __bf16*)wsb;           // 24 frag-tiles
    const __bf16* wp2 = (const __bf16*)(wsb + 49152); // 8 frag-tiles

    const int tid = threadIdx.x;
    const int bn  = blockIdx.x;
    const int b   = bn >> 6;
    const int wi  = (bn >> 3) & 7;
    const int wj  = bn & 7;

    const int w  = tid >> 6;        // wave id = head id
    const int lr = tid & 15;        // lane % 16
    const int lg = (tid & 63) >> 4; // lane / 16
    const int ln = tid & 63;        // lane in wave

    // token -> rolled spatial offset table (used by epilogue)
    if (tid < NT_) {
        const int i1 = tid / 7, j1 = tid - 7 * i1;
        int gh = wi * 7 + i1 + SHIFT_; if (gh >= HW_) gh -= HW_;
        int gw = wj * 7 + j1 + SHIFT_; if (gw >= HW_) gw -= HW_;
        ((int*)(smc + TOFFB))[tid] = gh * HW_ + gw;
    }

    // ---------------- phase 1: x -> X (bf16 frag-order, 49 rows) ----------------
    for (int idx = tid; idx < 49 * 16; idx += 256) {
        const int g = idx & 15, tok = idx >> 4;
        const int i1 = tok / 7, j1 = tok - 7 * i1;
        int gh = wi * 7 + i1 + SHIFT_; if (gh >= HW_) gh -= HW_;
        int gw = wj * 7 + j1 + SHIFT_; if (gw >= HW_) gw -= HW_;
        const float* px = x + (((size_t)(b * HW_ + gh)) * HW_ + gw) * C_ + g * 8;
        float4 a0 = *(const float4*)(px);
        float4 a1 = *(const float4*)(px + 4);
        union { bf16x8 v; __bf16 e[8]; } u;
        u.e[0] = (__bf16)a0.x; u.e[1] = (__bf16)a0.y;
        u.e[2] = (__bf16)a0.z; u.e[3] = (__bf16)a0.w;
        u.e[4] = (__bf16)a1.x; u.e[5] = (__bf16)a1.y;
        u.e[6] = (__bf16)a1.z; u.e[7] = (__bf16)a1.w;
        *(bf16x8*)(smc + XB + q4(g, tok)) = u.v;
    }
    __syncthreads();  // b1: X (and toff) ready

    // ---------------- phase 2: QKV, wave w owns head w; Q/K -> x16 reg frags ----------------
    const float qscale = 0.17677669529663687f;
    const int vb = VB + w * 4096;
    s16x4 qf[2][4], ka[2][4];   // elem j = d offset 4*lg+j within 16-d tile

    #pragma unroll
    for (int pass = 0; pass < 3; ++pass) {
        const int mt0 = pass * 8 + 2 * w;
        f32x4 acc[2][4];
        #pragma unroll
        for (int i = 0; i < 2; ++i) {
            const f32x4 bv = *(const f32x4*)(b_qkv + (mt0 + i) * 16 + lg * 4);
            #pragma unroll
            for (int nt = 0; nt < 4; ++nt) acc[i][nt] = bv;
        }
        #pragma unroll
        for (int ks = 0; ks < 4; ++ks) {
            bf16x8 bfr[4];
            #pragma unroll
            for (int nt = 0; nt < 4; ++nt)   // tok>=49: in-bounds garbage, isolated (see map)
                bfr[nt] = *(const bf16x8*)(smc + XB + q4(ks * 4 + lg, nt * 16 + lr));
            __builtin_amdgcn_s_setprio(1);
            #pragma unroll
            for (int i = 0; i < 2; ++i) {
                bf16x8 afr = *(const bf16x8*)(wt2 + (((mt0 + i) * 4 + ks) << 9) + (ln << 3));
                #pragma unroll
                for (int nt = 0; nt < 4; ++nt)
                    acc[i][nt] = __builtin_amdgcn_mfma_f32_16x16x32_bf16(afr, bfr[nt], acc[i][nt], 0, 0, 0);
            }
            __builtin_amdgcn_s_setprio(0);
        }
        if (pass == 0) {            // Q -> x16 B-frags (scaled)
            #pragma unroll
            for (int i = 0; i < 2; ++i)
                #pragma unroll
                for (int nt = 0; nt < 4; ++nt) {
                    union { s16x4 v; __bf16 e[4]; } u;
                    #pragma unroll
                    for (int r = 0; r < 4; ++r) u.e[r] = (__bf16)(acc[i][nt][r] * qscale);
                    qf[i][nt] = u.v;
                }
        } else if (pass == 1) {     // K -> x16 A-frags
            #pragma unroll
            for (int i = 0; i < 2; ++i)
                #pragma unroll
                for (int nt = 0; nt < 4; ++nt) {
                    union { s16x4 v; __bf16 e[4]; } u;
                    #pragma unroll
                    for (int r = 0; r < 4; ++r) u.e[r] = (__bf16)acc[i][nt][r];
                    ka[i][nt] = u.v;
                }
        } else {                    // V -> own LDS region; keys 49..63 ZERO
            #pragma unroll
            for (int i = 0; i < 2; ++i)
                #pragma unroll
                for (int nt = 0; nt < 4; ++nt) {
                    const int tok = nt * 16 + lr;
                    #pragma unroll
                    for (int r = 0; r < 4; ++r) {
                        const int d = i * 16 + lg * 4 + r;
                        const unsigned short val =
                            (tok < NT_) ? bfbits(acc[i][nt][r]) : (unsigned short)0;
                        *(unsigned short*)(smc + vb + swzv(tok >> 3, d) + ((tok & 7) << 1)) = val;
                    }
                }
        }
    }

    // va preload (own V, same-wave write->read): x16 A-frags (d=mtd*16+lr, key=kt*16+4lg+j)
    s16x4 va[2][4];
    #pragma unroll
    for (int mtd = 0; mtd < 2; ++mtd)
        #pragma unroll
        for (int kt = 0; kt < 4; ++kt)
            va[mtd][kt] = *(const s16x4*)(smc + vb
                + swzv(kt * 2 + (lg >> 1), mtd * 16 + lr) + ((lg & 1) << 3));

    __syncthreads();  // b2: all waves' X reads done -> X2 overlay of X safe

    // ---------------- phase 3: attention, fully register-resident ----------------
    const int cls = ((wi == 7) ? 2 : 0) | ((wj == 7) ? 1 : 0);
    const float* cbw = cb + (((size_t)(cls * 4 + w)) * 49) * 64;

    #pragma unroll
    for (int nt = 0; nt < 4; ++nt) {
        // S^T column tile (keys x q), K=16 MFMAs on reg fragments
        f32x4 sn[4];
        __builtin_amdgcn_s_setprio(1);
        #pragma unroll
        for (int mt = 0; mt < 4; ++mt) {
            f32x4 z = {0.f, 0.f, 0.f, 0.f};
            z = __builtin_amdgcn_mfma_f32_16x16x16bf16_1k(ka[0][mt], qf[0][nt], z, 0, 0, 0);
            sn[mt] = __builtin_amdgcn_mfma_f32_16x16x16bf16_1k(ka[1][mt], qf[1][nt], z, 0, 0, 0);
        }
        __builtin_amdgcn_s_setprio(0);
        // softmax over valid keys (key = mt*16 + 4*lg + r < 49); no max-shift (R14)
        float sum = 0.f;
        #pragma unroll
        for (int mt = 0; mt < 3; ++mt)
            #pragma unroll
            for (int r = 0; r < 4; ++r) {
                const float e = __expf(sn[mt][r]);
                sn[mt][r] = e; sum += e;
            }
        {
            const float e = (lg == 0) ? __expf(sn[3][0]) : 0.f;
            sn[3][0] = e;
            sum += e;
        }
        sum += __shfl_xor(sum, 16);
        sum += __shfl_xor(sum, 32);
        const float rs = 1.0f / sum;

        const int q  = nt * 16 + lr;
        const int qc = (q < NT_) ? q : 48;
        const float* cbq = cbw + qc * 64;

        // post-softmax bias+mask; P packs straight into x16 B-frags (no LDS)
        s16x4 pf[4];
        #pragma unroll
        for (int mt = 0; mt < 4; ++mt) {
            const f32x4 bv = *(const f32x4*)(cbq + mt * 16 + lg * 4);
            union { s16x4 v; __bf16 e[4]; } u;
            #pragma unroll
            for (int r = 0; r < 4; ++r) {
                const bool valid = (mt < 3) || (lg == 0 && r == 0);
                const float p = fmaf(sn[mt][r], rs, bv[r]);
                u.e[r] = valid ? (__bf16)p : (__bf16)0.0f;
            }
            pf[mt] = u.v;
        }
        // PV, per-nt accumulators
        f32x4 o0 = {0.f, 0.f, 0.f, 0.f}, o1 = {0.f, 0.f, 0.f, 0.f};
        __builtin_amdgcn_s_setprio(1);
        #pragma unroll
        for (int kt = 0; kt < 4; ++kt) {
            o0 = __builtin_amdgcn_mfma_f32_16x16x16bf16_1k(va[0][kt], pf[kt], o0, 0, 0, 0);
            o1 = __builtin_amdgcn_mfma_f32_16x16x16bf16_1k(va[1][kt], pf[kt], o1, 0, 0, 0);
        }
        __builtin_amdgcn_s_setprio(0);
        // X2 scatter into X region (own head's g-range 4w..4w+3; safe post-b2)
        if (q < NT_) {
            const int inner = (lg & 1) << 3;
            union { short4 s4; __bf16 e[4]; } pk0, pk1;
            #pragma unroll
            for (int r = 0; r < 4; ++r) { pk0.e[r] = (__bf16)o0[r]; pk1.e[r] = (__bf16)o1[r]; }
            *(short4*)(smc + XB + q4(w * 4 + 0 + (lg >> 1), q) + inner) = pk0.s4;
            *(short4*)(smc + XB + q4(w * 4 + 2 + (lg >> 1), q) + inner) = pk1.s4;
        }
    }

    // hoist proj weight fragments (global, no LDS dep) before the barrier
    bf16x8 bfpR[2][4];
    #pragma unroll
    for (int ntl = 0; ntl < 2; ++ntl)
        #pragma unroll
        for (int ks = 0; ks < 4; ++ks)
            bfpR[ntl][ks] = *(const bf16x8*)(wp2 + (((w * 2 + ntl) * 4 + ks) << 9) + (ln << 3));
    __syncthreads();  // b3: all heads' X2 complete

    // ---------------- phase 4: proj = X2 @ Wp + store ----------------
    {
        const int* toff = (const int*)(smc + TOFFB);
        f32x4 pacc[4][2];
        #pragma unroll
        for (int ntl = 0; ntl < 2; ++ntl) {
            const float bv = b_proj[(w * 2 + ntl) * 16 + lr];
            #pragma unroll
            for (int mt = 0; mt < 4; ++mt) {
                f32x4 v = {bv, bv, bv, bv};
                pacc[mt][ntl] = v;
            }
        }
        #pragma unroll
        for (int ks = 0; ks < 4; ++ks) {
            bf16x8 af[4];
            #pragma unroll
            for (int mt = 0; mt < 4; ++mt)   // rows>=49: garbage, rows discarded
                af[mt] = *(const bf16x8*)(smc + XB + q4(ks * 4 + lg, mt * 16 + lr));
            __builtin_amdgcn_s_setprio(1);
            #pragma unroll
            for (int mt = 0; mt < 4; ++mt)
                #pragma unroll
                for (int ntl = 0; ntl < 2; ++ntl)
                    pacc[mt][ntl] = __builtin_amdgcn_mfma_f32_16x16x32_bf16(af[mt], bfpR[ntl][ks], pacc[mt][ntl], 0, 0, 0);
            __builtin_amdgcn_s_setprio(0);
        }
        #pragma unroll
        for (int mt = 0; mt < 4; ++mt)
            #pragma unroll
            for (int r = 0; r < 4; ++r) {
                const int tok = mt * 16 + lg * 4 + r;
                if (tok < NT_) {
                    float* po = out + (((size_t)b * (HW_ * HW_)) + toff[tok]) * C_;
                    #pragma unroll
                    for (int ntl = 0; ntl < 2; ++ntl)
                        po[(w * 2 + ntl) * 16 + lr] = pacc[mt][ntl][r];
                }
            }
    }
}

extern "C" void kernel_launch(void* const* d_in, const int* in_sizes, int n_in,
                              void* d_out, int out_size, void* d_ws, size_t ws_size,
                              hipStream_t stream) {
    const float* x      = (const float*)d_in[0];
    const float* w_qkv  = (const float*)d_in[1];
    const float* b_qkv  = (const float*)d_in[2];
    const float* w_proj = (const float*)d_in[3];
    const float* b_proj = (const float*)d_in[4];
    const float* rel    = (const float*)d_in[5];
    float* outp = (float*)d_out;
    unsigned short* wsb = (unsigned short*)d_ws;
    float* cbp = (float*)((char*)d_ws + WS_CB_BYTE);

    hipLaunchKernelGGL(prep, dim3((65536 + CB_ELEMS + 255) / 256), dim3(256), 0, stream,
                       w_qkv, w_proj, rel, wsb, cbp);
    hipLaunchKernelGGL(swin_fused, dim3(4096), dim3(256), SMEMB, stream,
                       x, b_qkv, b_proj, wsb, cbp, outp);
}

// Round 16
// 84.368 us; speedup vs baseline: 1.2336x; 1.2336x over previous
//
#include <hip/hip_runtime.h>

#define HW_    56
#define C_     128
#define SHIFT_ 3
#define NH_    4
#define NT_    49

typedef __attribute__((ext_vector_type(8))) __bf16 bf16x8;
typedef __attribute__((ext_vector_type(4))) float  f32x4;
typedef __attribute__((ext_vector_type(4))) short  s16x4;

// d_ws layout:
//   shorts [0, 65536)       : wt2 (24 qkv oc-tiles) then wp2 (8 proj oc-tiles),
//                             FRAGMENT-CONTIGUOUS (R12): block (tile,ks)=512 bf16,
//                             lane L holds (oc=tile*16+(L&15), ic=ks*32+(L>>4)*8+e).
//   bytes [131072, +200704) : f32 cb[cls=4][h=4][q=49][k=64] — bias+mask
//                             (post-softmax). Mask depends ONLY on (wi==7,wj==7).
#define WS_CB_BYTE  131072
#define CB_ELEMS    (4 * 4 * 49 * 64)

// LDS 29440 B, (256,4) — occupancy ceiling is 4 blocks/CU (R15 proved (256,5)
// spills: true reg need ~120 combined).
// [0,12800):  X [16 g][49 tok][16B] stride 784 identity. NEVER overwritten
//   (R16: X2 moved to V region) -> phase-2 reads race-free, b2 deleted.
// [12800,29184): V per head h at VB+h*4096: [8 oct][32 d][16B] swzv, ALL
//   4096 B written (keys>=49 ZERO — PV reduction axis, NaN*0=NaN). After the
//   wave's own va preload, X2 overlays OWN head's V: [4 sub][49 tok][16B]
//   stride 784 (3136 B; bytes beyond hold stale-but-finite V). Wave-private
//   write; cross-wave read (phase 4) is protected by the pre-proj barrier.
// [29184,29380): toff. Q,K,S,P reg-resident. Softmax without max-shift (R14):
//   S=QK^T pre-bias, |S|<~0.5 here; exp overflow needs |S|>80.
#define XB    0
#define VB    12800
#define TOFFB 29184
#define SMEMB 29440

__device__ __forceinline__ int q4(int g, int tok) { return g * 784 + (tok << 4); }
__device__ __forceinline__ int swzv(int g, int row) {
    return (((g << 9) + (row << 4)) ^ ((g & 7) << 4));
}
__device__ __forceinline__ int x2adr(int g, int tok) {  // X2 over V region
    return VB + (g >> 2) * 4096 + (g & 3) * 784 + (tok << 4);
}
__device__ __forceinline__ unsigned short bfbits(float f) {
    __bf16 h = (__bf16)f;
    union { __bf16 b; unsigned short u; } c; c.b = h; return c.u;
}

// ---- fused prep: weights (frag-contiguous bf16) + cb class table ----
__global__ void prep(const float* __restrict__ wq, const float* __restrict__ wp,
                     const float* __restrict__ rel, unsigned short* __restrict__ ws,
                     float* __restrict__ cb) {
    int i = blockIdx.x * 256 + threadIdx.x;
    if (i < 49152) {
        const int mt   = i >> 11;
        const int ks   = (i >> 9) & 3;
        const int lane = (i >> 3) & 63;
        const int e    = i & 7;
        const int oc   = mt * 16 + (lane & 15);
        const int ic   = ks * 32 + (lane >> 4) * 8 + e;
        ws[i] = bfbits(wq[ic * 384 + oc]);
    } else if (i < 65536) {
        const int j    = i - 49152;
        const int t    = j >> 11;
        const int ks   = (j >> 9) & 3;
        const int lane = (j >> 3) & 63;
        const int e    = j & 7;
        const int oc   = t * 16 + (lane & 15);
        const int ic   = ks * 32 + (lane >> 4) * 8 + e;
        ws[i] = bfbits(wp[ic * 128 + oc]);
    } else {
        const int j = i - 65536;
        if (j < CB_ELEMS) {
            const int k = j & 63;
            const int t = j >> 6;          // (cls*4 + h)*49 + q
            const int q = t % 49;
            const int u = t / 49;
            const int h = u & 3;
            const int cls = u >> 2;        // 2*(wi==7) + (wj==7)
            float v = 0.f;
            if (k < 49) {
                const int iq = q / 7, jq = q - 7 * iq;
                const int ik = k / 7, jk = k - 7 * ik;
                v = rel[((iq - ik + 6) * 13 + (jq - jk + 6)) * NH_ + h];
                const int rq = ((cls >> 1) ? (iq < 4 ? 1 : 2) : 0) * 3
                             + ((cls & 1) ? (jq < 4 ? 1 : 2) : 0);
                const int rk = ((cls >> 1) ? (ik < 4 ? 1 : 2) : 0) * 3
                             + ((cls & 1) ? (jk < 4 ? 1 : 2) : 0);
                if (rq != rk) v -= 100.0f;
            }
            cb[j] = v;
        }
    }
}

__global__ __launch_bounds__(256, 4)
void swin_fused(const float* __restrict__ x,
                const float* __restrict__ b_qkv,
                const float* __restrict__ b_proj,
                const unsigned short* __restrict__ wsb,
                const float* __restrict__ cb,
                float* __restrict__ out)
{
    extern __shared__ char smc[];
    const __bf16* wt2 = (const __bf16*)wsb;           // 24 frag-tiles
    const __bf16* wp2 = (const __bf16*)(wsb + 49152); // 8 frag-tiles

    const int tid = threadIdx.x;
    const int bn  = blockIdx.x;
    const int b   = bn >> 6;
    const int wi  = (bn >> 3) & 7;
    const int wj  = bn & 7;

    const int w  = tid >> 6;        // wave id = head id
    const int lr = tid & 15;        // lane % 16
    const int lg = (tid & 63) >> 4; // lane / 16
    const int ln = tid & 63;        // lane in wave

    // token -> rolled spatial offset table (used by epilogue)
    if (tid < NT_) {
        const int i1 = tid / 7, j1 = tid - 7 * i1;
        int gh = wi * 7 + i1 + SHIFT_; if (gh >= HW_) gh -= HW_;
        int gw = wj * 7 + j1 + SHIFT_; if (gw >= HW_) gw -= HW_;
        ((int*)(smc + TOFFB))[tid] = gh * HW_ + gw;
    }

    // ---------------- phase 1: x -> X (bf16 frag-order, 49 rows) ----------------
    for (int idx = tid; idx < 49 * 16; idx += 256) {
        const int g = idx & 15, tok = idx >> 4;
        const int i1 = tok / 7, j1 = tok - 7 * i1;
        int gh = wi * 7 + i1 + SHIFT_; if (gh >= HW_) gh -= HW_;
        int gw = wj * 7 + j1 + SHIFT_; if (gw >= HW_) gw -= HW_;
        const float* px = x + (((size_t)(b * HW_ + gh)) * HW_ + gw) * C_ + g * 8;
        float4 a0 = *(const float4*)(px);
        float4 a1 = *(const float4*)(px + 4);
        union { bf16x8 v; __bf16 e[8]; } u;
        u.e[0] = (__bf16)a0.x; u.e[1] = (__bf16)a0.y;
        u.e[2] = (__bf16)a0.z; u.e[3] = (__bf16)a0.w;
        u.e[4] = (__bf16)a1.x; u.e[5] = (__bf16)a1.y;
        u.e[6] = (__bf16)a1.z; u.e[7] = (__bf16)a1.w;
        *(bf16x8*)(smc + XB + q4(g, tok)) = u.v;
    }
    __syncthreads();  // b1: X (and toff) ready

    // ---------------- phase 2: QKV, wave w owns head w; Q/K -> x16 reg frags ----------------
    const float qscale = 0.17677669529663687f;
    const int vb = VB + w * 4096;
    s16x4 qf[2][4], ka[2][4];   // elem j = d offset 4*lg+j within 16-d tile

    #pragma unroll
    for (int pass = 0; pass < 3; ++pass) {
        const int mt0 = pass * 8 + 2 * w;
        f32x4 acc[2][4];
        #pragma unroll
        for (int i = 0; i < 2; ++i) {
            const f32x4 bv = *(const f32x4*)(b_qkv + (mt0 + i) * 16 + lg * 4);
            #pragma unroll
            for (int nt = 0; nt < 4; ++nt) acc[i][nt] = bv;
        }
        #pragma unroll
        for (int ks = 0; ks < 4; ++ks) {
            bf16x8 bfr[4];
            #pragma unroll
            for (int nt = 0; nt < 4; ++nt)   // tok>=49: in-bounds garbage, isolated (see map)
                bfr[nt] = *(const bf16x8*)(smc + XB + q4(ks * 4 + lg, nt * 16 + lr));
            __builtin_amdgcn_s_setprio(1);
            #pragma unroll
            for (int i = 0; i < 2; ++i) {
                bf16x8 afr = *(const bf16x8*)(wt2 + (((mt0 + i) * 4 + ks) << 9) + (ln << 3));
                #pragma unroll
                for (int nt = 0; nt < 4; ++nt)
                    acc[i][nt] = __builtin_amdgcn_mfma_f32_16x16x32_bf16(afr, bfr[nt], acc[i][nt], 0, 0, 0);
            }
            __builtin_amdgcn_s_setprio(0);
        }
        if (pass == 0) {            // Q -> x16 B-frags (scaled)
            #pragma unroll
            for (int i = 0; i < 2; ++i)
                #pragma unroll
                for (int nt = 0; nt < 4; ++nt) {
                    union { s16x4 v; __bf16 e[4]; } u;
                    #pragma unroll
                    for (int r = 0; r < 4; ++r) u.e[r] = (__bf16)(acc[i][nt][r] * qscale);
                    qf[i][nt] = u.v;
                }
        } else if (pass == 1) {     // K -> x16 A-frags
            #pragma unroll
            for (int i = 0; i < 2; ++i)
                #pragma unroll
                for (int nt = 0; nt < 4; ++nt) {
                    union { s16x4 v; __bf16 e[4]; } u;
                    #pragma unroll
                    for (int r = 0; r < 4; ++r) u.e[r] = (__bf16)acc[i][nt][r];
                    ka[i][nt] = u.v;
                }
        } else {                    // V -> own LDS region; keys 49..63 ZERO
            #pragma unroll
            for (int i = 0; i < 2; ++i)
                #pragma unroll
                for (int nt = 0; nt < 4; ++nt) {
                    const int tok = nt * 16 + lr;
                    #pragma unroll
                    for (int r = 0; r < 4; ++r) {
                        const int d = i * 16 + lg * 4 + r;
                        const unsigned short val =
                            (tok < NT_) ? bfbits(acc[i][nt][r]) : (unsigned short)0;
                        *(unsigned short*)(smc + vb + swzv(tok >> 3, d) + ((tok & 7) << 1)) = val;
                    }
                }
        }
    }

    // va preload (own V, same-wave write->read): x16 A-frags (d=mtd*16+lr, key=kt*16+4lg+j)
    s16x4 va[2][4];
    #pragma unroll
    for (int mtd = 0; mtd < 2; ++mtd)
        #pragma unroll
        for (int kt = 0; kt < 4; ++kt)
            va[mtd][kt] = *(const s16x4*)(smc + vb
                + swzv(kt * 2 + (lg >> 1), mtd * 16 + lr) + ((lg & 1) << 3));
    // NO barrier here (R16): X is never overwritten; X2 goes to the wave's
    // OWN dead V region (private). Attention starts immediately.

    // ---------------- phase 3: attention, fully register-resident ----------------
    const int cls = ((wi == 7) ? 2 : 0) | ((wj == 7) ? 1 : 0);
    const float* cbw = cb + (((size_t)(cls * 4 + w)) * 49) * 64;

    #pragma unroll
    for (int nt = 0; nt < 4; ++nt) {
        // S^T column tile (keys x q), K=16 MFMAs on reg fragments
        f32x4 sn[4];
        __builtin_amdgcn_s_setprio(1);
        #pragma unroll
        for (int mt = 0; mt < 4; ++mt) {
            f32x4 z = {0.f, 0.f, 0.f, 0.f};
            z = __builtin_amdgcn_mfma_f32_16x16x16bf16_1k(ka[0][mt], qf[0][nt], z, 0, 0, 0);
            sn[mt] = __builtin_amdgcn_mfma_f32_16x16x16bf16_1k(ka[1][mt], qf[1][nt], z, 0, 0, 0);
        }
        __builtin_amdgcn_s_setprio(0);
        // softmax over valid keys (key = mt*16 + 4*lg + r < 49); no max-shift (R14)
        float sum = 0.f;
        #pragma unroll
        for (int mt = 0; mt < 3; ++mt)
            #pragma unroll
            for (int r = 0; r < 4; ++r) {
                const float e = __expf(sn[mt][r]);
                sn[mt][r] = e; sum += e;
            }
        {
            const float e = (lg == 0) ? __expf(sn[3][0]) : 0.f;
            sn[3][0] = e;
            sum += e;
        }
        sum += __shfl_xor(sum, 16);
        sum += __shfl_xor(sum, 32);
        const float rs = 1.0f / sum;

        const int q  = nt * 16 + lr;
        const int qc = (q < NT_) ? q : 48;
        const float* cbq = cbw + qc * 64;

        // post-softmax bias+mask; P packs straight into x16 B-frags (no LDS)
        s16x4 pf[4];
        #pragma unroll
        for (int mt = 0; mt < 4; ++mt) {
            const f32x4 bv = *(const f32x4*)(cbq + mt * 16 + lg * 4);
            union { s16x4 v; __bf16 e[4]; } u;
            #pragma unroll
            for (int r = 0; r < 4; ++r) {
                const bool valid = (mt < 3) || (lg == 0 && r == 0);
                const float p = fmaf(sn[mt][r], rs, bv[r]);
                u.e[r] = valid ? (__bf16)p : (__bf16)0.0f;
            }
            pf[mt] = u.v;
        }
        // PV, per-nt accumulators
        f32x4 o0 = {0.f, 0.f, 0.f, 0.f}, o1 = {0.f, 0.f, 0.f, 0.f};
        __builtin_amdgcn_s_setprio(1);
        #pragma unroll
        for (int kt = 0; kt < 4; ++kt) {
            o0 = __builtin_amdgcn_mfma_f32_16x16x16bf16_1k(va[0][kt], pf[kt], o0, 0, 0, 0);
            o1 = __builtin_amdgcn_mfma_f32_16x16x16bf16_1k(va[1][kt], pf[kt], o1, 0, 0, 0);
        }
        __builtin_amdgcn_s_setprio(0);
        // X2 scatter into OWN head's dead V region (wave-private; va already in regs)
        if (q < NT_) {
            const int inner = (lg & 1) << 3;
            union { short4 s4; __bf16 e[4]; } pk0, pk1;
            #pragma unroll
            for (int r = 0; r < 4; ++r) { pk0.e[r] = (__bf16)o0[r]; pk1.e[r] = (__bf16)o1[r]; }
            *(short4*)(smc + x2adr(w * 4 + 0 + (lg >> 1), q) + inner) = pk0.s4;
            *(short4*)(smc + x2adr(w * 4 + 2 + (lg >> 1), q) + inner) = pk1.s4;
        }
    }

    // hoist proj weight fragments (global, no LDS dep) before the barrier
    bf16x8 bfpR[2][4];
    #pragma unroll
    for (int ntl = 0; ntl < 2; ++ntl)
        #pragma unroll
        for (int ks = 0; ks < 4; ++ks)
            bfpR[ntl][ks] = *(const bf16x8*)(wp2 + (((w * 2 + ntl) * 4 + ks) << 9) + (ln << 3));
    __syncthreads();  // b2: all heads' X2 complete

    // ---------------- phase 4: proj = X2 @ Wp + store ----------------
    {
        const int* toff = (const int*)(smc + TOFFB);
        f32x4 pacc[4][2];
        #pragma unroll
        for (int ntl = 0; ntl < 2; ++ntl) {
            const float bv = b_proj[(w * 2 + ntl) * 16 + lr];
            #pragma unroll
            for (int mt = 0; mt < 4; ++mt) {
                f32x4 v = {bv, bv, bv, bv};
                pacc[mt][ntl] = v;
            }
        }
        #pragma unroll
        for (int ks = 0; ks < 4; ++ks) {
            bf16x8 af[4];
            #pragma unroll
            for (int mt = 0; mt < 4; ++mt)   // rows>=49: stale-but-finite V bytes, rows discarded
                af[mt] = *(const bf16x8*)(smc + x2adr(ks * 4 + lg, mt * 16 + lr));
            __builtin_amdgcn_s_setprio(1);
            #pragma unroll
            for (int mt = 0; mt < 4; ++mt)
                #pragma unroll
                for (int ntl = 0; ntl < 2; ++ntl)
                    pacc[mt][ntl] = __builtin_amdgcn_mfma_f32_16x16x32_bf16(af[mt], bfpR[ntl][ks], pacc[mt][ntl], 0, 0, 0);
            __builtin_amdgcn_s_setprio(0);
        }
        #pragma unroll
        for (int mt = 0; mt < 4; ++mt)
            #pragma unroll
            for (int r = 0; r < 4; ++r) {
                const int tok = mt * 16 + lg * 4 + r;
                if (tok < NT_) {
                    float* po = out + (((size_t)b * (HW_ * HW_)) + toff[tok]) * C_;
                    #pragma unroll
                    for (int ntl = 0; ntl < 2; ++ntl)
                        po[(w * 2 + ntl) * 16 + lr] = pacc[mt][ntl][r];
                }
            }
    }
}

extern "C" void kernel_launch(void* const* d_in, const int* in_sizes, int n_in,
                              void* d_out, int out_size, void* d_ws, size_t ws_size,
                              hipStream_t stream) {
    const float* x      = (const float*)d_in[0];
    const float* w_qkv  = (const float*)d_in[1];
    const float* b_qkv  = (const float*)d_in[2];
    const float* w_proj = (const float*)d_in[3];
    const float* b_proj = (const float*)d_in[4];
    const float* rel    = (const float*)d_in[5];
    float* outp = (float*)d_out;
    unsigned short* wsb = (unsigned short*)d_ws;
    float* cbp = (float*)((char*)d_ws + WS_CB_BYTE);

    hipLaunchKernelGGL(prep, dim3((65536 + CB_ELEMS + 255) / 256), dim3(256), 0, stream,
                       w_qkv, w_proj, rel, wsb, cbp);
    hipLaunchKernelGGL(swin_fused, dim3(4096), dim3(256), SMEMB, stream,
                       x, b_qkv, b_proj, wsb, cbp, outp);
}